// Round 16
// baseline (250.960 us; speedup 1.0000x reference)
//
#include <hip/hip_runtime.h>
#include <hip/hip_bf16.h>
#include <stdint.h>

// ---------------------------------------------------------------------------
// RG-LRU block: T=8192, D_MODEL=768, D_RNN=1024, KW=4.
// Round 20 (on R15's 247us pipeline): convx residency push.
//  - convx BN 128->64 (NI=2): B-frags JIT to regs (no dbuf; 8 frags = 32
//    VGPR), acc 32 AGPR, ~105 unified regs -> 4 waves/SIMD; LDS arena 17KB;
//    launch_bounds(256,4) -> 4 blocks/CU (was 2).  32 MFMA/wave/barrier.
//    Grid 64x16 fully resident.  vmcnt(2) FIFO (retires B(t)+A(t)).
//  - dense GEMM template (BK=64), Vgemm EPI=3, scans NC=256, prep1:
//    byte-identical to R15.
// ---------------------------------------------------------------------------

#define T_LEN 8192
#define DM 768
#define DR 1024
#define NC 256   // scan chunks
#define CL 32    // chunk length

typedef __bf16 bf16x8 __attribute__((ext_vector_type(8)));
typedef float  f32x4  __attribute__((ext_vector_type(4)));

#define AS1 __attribute__((address_space(1)))
#define AS3 __attribute__((address_space(3)))

__device__ __forceinline__ void cp16_g2l(const void* g, void* l) {
    __builtin_amdgcn_global_load_lds((const AS1 void*)g, (AS3 void*)l, 16, 0, 0);
}

__device__ __forceinline__ float gelu_tanh(float x) {
    const float inner = 0.7978845608028654f * (x + 0.044715f * x * x * x);
    return 0.5f * x * (1.f + tanhf(inner));
}

__device__ __forceinline__ __bf16 f2b(float v) {
    __hip_bfloat16 h = __float2bfloat16(v);
    return *reinterpret_cast<__bf16*>(&h);
}

// ---------------------------------------------------------------------------
// Dense GEMM (R15-verified), BN=64, BK=64/iter, 4 blocks/CU.
// A: LDS dbuf [2][128*64]; 8 chunks/row; slot s of row r holds chunk s^(r&7).
// B: fragment-major WF [ntile][kt][lane][16B]; 2 ksteps x NI=2 frags jit.
// EPI: 0 = fp32 +bias; 1 = bf16 +bias; 2 = bf16 gelu (stride-1024);
//      3 = bf16 -> conv frag-major WBf (Vgemm).
// ---------------------------------------------------------------------------
template<int EPI>
__global__ __launch_bounds__(256, 4)
void gemm_mfma(const __hip_bfloat16* __restrict__ A,
               const __hip_bfloat16* __restrict__ WF,
               const float* __restrict__ bias,
               void* __restrict__ Cv,
               int K, int lda, int N,
               __hip_bfloat16* __restrict__ D2)
{
    __shared__ __align__(16) unsigned char smem[32768];
    __bf16* Asb = (__bf16*)smem;           // [2][128*64] = 32KB

    const int tid  = threadIdx.x;
    const int lane = tid & 63;
    const int wave = tid >> 6;
    const size_t m0 = (size_t)blockIdx.x * 128;
    const int    n0 = blockIdx.y * 64;
    const int wm = (wave >> 1) * 64;
    const int wn = (wave & 1) * 32;

    f32x4 acc[4][2];
#pragma unroll
    for (int i = 0; i < 4; ++i)
#pragma unroll
        for (int j = 0; j < 2; ++j)
            acc[i][j] = f32x4{0.f, 0.f, 0.f, 0.f};

    const int frow = lane & 15;
    const int fq   = lane >> 4;
    const int NKT  = K >> 5;                // 32-col k-steps
    const int nt   = K >> 6;                // 64-col iterations

    const __bf16* wbase = (const __bf16*)WF +
        (((size_t)((n0 + wn) >> 4) * NKT) << 9) + (lane << 3);

    auto stageA = [&](int buf, int k0) {   // 128 rows x 8 chunks = 1024 chunks
#pragma unroll
        for (int q = 0; q < 4; ++q) {
            const int lin = q * 256 + tid;
            const int rr  = lin >> 3;
            const int gc  = (lin & 7) ^ (rr & 7);
            cp16_g2l(A + (m0 + rr) * (size_t)lda + k0 + gc * 8,
                     Asb + buf * 8192 + lin * 8);
        }
    };

    stageA(0, 0);
#pragma unroll 1
    for (int t = 0; t < nt; ++t) {
        bf16x8 bfr[2][2];
#pragma unroll
        for (int ks = 0; ks < 2; ++ks)
#pragma unroll
            for (int ni = 0; ni < 2; ++ni)
                bfr[ks][ni] = *(const bf16x8*)(wbase +
                    (((size_t)(ni * NKT + 2 * t + ks)) << 9));
        if (t + 1 < nt) {
            stageA((t + 1) & 1, (t + 1) * 64);
            // FIFO: [A(t):4][B(t):4][A(t+1):4]; vmcnt(4) retires A(t)+B(t)
            asm volatile("s_waitcnt vmcnt(4)" ::: "memory");
        } else {
            asm volatile("s_waitcnt vmcnt(0)" ::: "memory");
        }
        __builtin_amdgcn_sched_barrier(0);
        __builtin_amdgcn_s_barrier();          // A[t&1] staged for all waves
        __builtin_amdgcn_sched_barrier(0);

        const int ab = (t & 1) * 8192;
        bf16x8 af[2][4];
#pragma unroll
        for (int ks = 0; ks < 2; ++ks)
#pragma unroll
            for (int mi = 0; mi < 4; ++mi) {
                const int R = wm + mi * 16 + frow;
                af[ks][mi] = *(const bf16x8*)&Asb[ab + R * 64 +
                                                  (((ks * 4 + fq) ^ (R & 7)) * 8)];
            }
        asm volatile("s_waitcnt lgkmcnt(0)" ::: "memory");
        __builtin_amdgcn_sched_barrier(0);
        __builtin_amdgcn_s_setprio(1);
#pragma unroll
        for (int ks = 0; ks < 2; ++ks)
#pragma unroll
            for (int mi = 0; mi < 4; ++mi)
#pragma unroll
                for (int ni = 0; ni < 2; ++ni)
                    acc[mi][ni] = __builtin_amdgcn_mfma_f32_16x16x32_bf16(
                        af[ks][mi], bfr[ks][ni], acc[mi][ni], 0, 0, 0);
        __builtin_amdgcn_s_setprio(0);
        __builtin_amdgcn_sched_barrier(0);
        __builtin_amdgcn_s_barrier();          // A[t&1] free for overwrite
        __builtin_amdgcn_sched_barrier(0);
    }

    // ---- epilogue: acc -> swizzled LDS -> coalesced 16B/lane global stores.
    __syncthreads();
    const int er = fq * 4;
    const int ec = frow;

    if (EPI == 0) {
        float* Cl = (float*)smem;
#pragma unroll
        for (int ni = 0; ni < 2; ++ni) {
            const int cc = wn + ni * 16 + ec;
            const float bv = bias ? bias[n0 + cc] : 0.f;
#pragma unroll
            for (int mi = 0; mi < 4; ++mi)
#pragma unroll
                for (int r2 = 0; r2 < 4; ++r2) {
                    const int R = wm + mi * 16 + er + r2;
                    Cl[R * 64 + ((((cc >> 2) ^ (R & 7)) << 2) | (cc & 3))] =
                        acc[mi][ni][r2] + bv;
                }
        }
        __syncthreads();
        float* outp = (float*)Cv;
#pragma unroll
        for (int p = 0; p < 8; ++p) {
            const int R   = (tid >> 4) + p * 16;
            const int chn = tid & 15;
            const f32x4 v = *(const f32x4*)&Cl[R * 64 + ((chn ^ (R & 7)) << 2)];
            *(f32x4*)&outp[(m0 + R) * (size_t)N + n0 + chn * 4] = v;
        }
    } else {
        __bf16* Cl = (__bf16*)smem;
#pragma unroll
        for (int ni = 0; ni < 2; ++ni) {
            const int cc = wn + ni * 16 + ec;
            const float bv = bias ? bias[n0 + cc] : 0.f;
#pragma unroll
            for (int mi = 0; mi < 4; ++mi)
#pragma unroll
                for (int r2 = 0; r2 < 4; ++r2) {
                    const int R = wm + mi * 16 + er + r2;
                    float v = acc[mi][ni][r2] + bv;
                    if (EPI == 2) v = gelu_tanh(v);
                    Cl[R * 64 + ((((cc >> 3) ^ (R & 7)) << 3) | (cc & 7))] = f2b(v);
                }
        }
        __syncthreads();
#pragma unroll
        for (int p = 0; p < 4; ++p) {
            const int R   = (tid >> 3) + p * 32;
            const int chn = tid & 7;
            const bf16x8 v = *(const bf16x8*)&Cl[R * 64 + ((chn ^ (R & 7)) << 3)];
            if (EPI == 1) {
                *(bf16x8*)((__bf16*)Cv + (m0 + R) * (size_t)N + n0 + chn * 8) = v;
            } else if (EPI == 2) {
                *(bf16x8*)((__bf16*)Cv + (m0 + R) * 1024 + n0 + chn * 8) = v;
            } else {
                // EPI==3: conv frag-major WBf.  m = s*1024+o, j = col.
                const int m  = (int)(m0 + R);
                const int s  = m >> 10;
                const int o  = m & 1023;
                const int j  = n0 + chn * 8;
                const size_t dst = (size_t)(o >> 4) * 49152 + (size_t)(j >> 5) * 2048 +
                                   s * 512 + ((((j >> 3) & 3) * 16 + (o & 15)) << 3);
                *(bf16x8*)((__bf16*)Cv + dst) = v;
            }
        }
    }
    (void)D2;
}

// ---------------------------------------------------------------------------
// convx, BN=64, 4 blocks/CU: bc[t,o] = sum_s sum_j V[s][o][j]*xbp[t+s][j].
// B-frags (8) JIT global->reg from WBf [nt][kcI<24][s][lane][8]; A-halo
// (132x32) LDS dbuf; 32 MFMA/wave per barrier-pair; vmcnt(2) FIFO.
// Grid 64x16 = 1024 blocks, fully resident at 4/CU.
// ---------------------------------------------------------------------------
__global__ __launch_bounds__(256, 4)
void convx_mfma(const __hip_bfloat16* __restrict__ xbp,
                const __hip_bfloat16* __restrict__ WBf,
                __hip_bfloat16* __restrict__ C)
{
    __shared__ __align__(16) unsigned char smem[17408];
    __bf16* Ah = (__bf16*)smem;             // [2][132*32] halo dbuf (16.9KB)

    const int tid  = threadIdx.x;
    const int lane = tid & 63;
    const int wave = tid >> 6;
    const size_t m0 = (size_t)blockIdx.x * 128;
    const int    n0 = blockIdx.y * 64;
    const int wm = (wave >> 1) * 64;
    const int wn = (wave & 1) * 32;

    f32x4 acc[4][2];
#pragma unroll
    for (int i = 0; i < 4; ++i)
#pragma unroll
        for (int j = 0; j < 2; ++j)
            acc[i][j] = f32x4{0.f, 0.f, 0.f, 0.f};

    const int frow = lane & 15;
    const int fq   = lane >> 4;

    const __bf16* wbase = (const __bf16*)WBf +
        (size_t)((n0 + wn) >> 4) * 49152 + (lane << 3);

    auto stageA = [&](int abuf, int kc) {   // 132 rows x 4 chunks = 528 chunks
#pragma unroll
        for (int q = 0; q < 2; ++q) {
            const int lin = q * 256 + tid;
            const int rr  = lin >> 2;
            const int gc  = (lin & 3) ^ ((rr >> 1) & 3);
            cp16_g2l(xbp + (m0 + rr) * 768 + kc + gc * 8, Ah + abuf * 4224 + lin * 8);
        }
        if (tid < 16) {
            const int lin = 512 + tid;
            const int rr  = lin >> 2;
            const int gc  = (lin & 3) ^ ((rr >> 1) & 3);
            cp16_g2l(xbp + (m0 + rr) * 768 + kc + gc * 8, Ah + abuf * 4224 + lin * 8);
        }
    };

    stageA(0, 0);
#pragma unroll 1
    for (int t = 0; t < 24; ++t) {
        bf16x8 bfr[4][2];
#pragma unroll
        for (int s = 0; s < 4; ++s)
#pragma unroll
            for (int ni = 0; ni < 2; ++ni)
                bfr[s][ni] = *(const bf16x8*)(wbase + (size_t)ni * 49152 +
                                              t * 2048 + s * 512);
        if (t + 1 < 24) {
            stageA((t + 1) & 1, (t + 1) * 32);
            // FIFO: [B(t):8][A(t+1):2-3]; vmcnt(2) retires all B(t) (and the
            // previous iter's A(t), which is older).  tid<16's extra halo
            // load makes its wait marginally stronger -- safe direction.
            asm volatile("s_waitcnt vmcnt(2)" ::: "memory");
        } else {
            asm volatile("s_waitcnt vmcnt(0)" ::: "memory");
        }
        __builtin_amdgcn_sched_barrier(0);
        __builtin_amdgcn_s_barrier();          // halo[t&1] staged for all waves
        __builtin_amdgcn_sched_barrier(0);

        const int ab = (t & 1) * 4224;
        __builtin_amdgcn_s_setprio(1);
#pragma unroll
        for (int s = 0; s < 4; ++s) {
            bf16x8 af[4];
#pragma unroll
            for (int mi = 0; mi < 4; ++mi) {
                const int R = wm + mi * 16 + frow + s;       // shifted halo row
                af[mi] = *(const bf16x8*)&Ah[ab + R * 32 + ((fq ^ ((R >> 1) & 3)) * 8)];
            }
#pragma unroll
            for (int mi = 0; mi < 4; ++mi)
#pragma unroll
                for (int ni = 0; ni < 2; ++ni)
                    acc[mi][ni] = __builtin_amdgcn_mfma_f32_16x16x32_bf16(
                        af[mi], bfr[s][ni], acc[mi][ni], 0, 0, 0);
        }
        __builtin_amdgcn_s_setprio(0);
        __builtin_amdgcn_sched_barrier(0);
        __builtin_amdgcn_s_barrier();          // halo[t&1] free for overwrite
        __builtin_amdgcn_sched_barrier(0);
    }

    // ---- epilogue: bf16 tile 128x64 via swizzled LDS, coalesced stores.
    __syncthreads();
    const int er = fq * 4;
    const int ec = frow;
    __bf16* Cl = (__bf16*)smem;
#pragma unroll
    for (int ni = 0; ni < 2; ++ni) {
        const int cc = wn + ni * 16 + ec;
#pragma unroll
        for (int mi = 0; mi < 4; ++mi)
#pragma unroll
            for (int r2 = 0; r2 < 4; ++r2) {
                const int R = wm + mi * 16 + er + r2;
                Cl[R * 64 + ((((cc >> 3) ^ (R & 7)) << 3) | (cc & 7))] =
                    f2b(acc[mi][ni][r2]);
            }
    }
    __syncthreads();
#pragma unroll
    for (int p = 0; p < 4; ++p) {
        const int R   = (tid >> 3) + p * 32;
        const int chn = tid & 7;
        const bf16x8 v = *(const bf16x8*)&Cl[R * 64 + ((chn ^ (R & 7)) << 3)];
        *(bf16x8*)((__bf16*)C + (m0 + R) * 1024 + n0 + chn * 8) = v;
    }
}

// ---------------------------------------------------------------------------
// prep1 (byte-identical to R15): xbp (3 zero rows) + w1f (gelu half) +
// w1bT (Vgemm B) + cwr (Vgemm A) + w_rgf + w_outf.
// ---------------------------------------------------------------------------
#define P_XBP  6293760              // 8195*768
#define P_W1F  (P_XBP + 786432)     // 64nt * 24kt * 512
#define P_W1BT (P_W1F + 786432)     // 48nt * 32kt * 512
#define P_CWR  (P_W1BT + 4194304)   // 4096*1024
#define P_WRG  (P_CWR + 2097152)    // 128nt * 32kt * 512
#define P_WO   (P_WRG + 786432)     // 48nt * 32kt * 512
#define P_TOT  P_WO                 // 14,944,512 = 256 * 58377
__global__ void prep1_kernel(const float* __restrict__ x, const float* __restrict__ w1,
                             const float* __restrict__ w_rg, const float* __restrict__ w_out,
                             const float* __restrict__ conv_w,
                             __hip_bfloat16* __restrict__ xbp, __hip_bfloat16* __restrict__ w1f,
                             __hip_bfloat16* __restrict__ w1bT, __hip_bfloat16* __restrict__ cwr,
                             __hip_bfloat16* __restrict__ w_rgf, __hip_bfloat16* __restrict__ w_outf)
{
    const int idx = blockIdx.x * 256 + threadIdx.x;
    if (idx < P_XBP) {
        xbp[idx] = (idx < 2304) ? __float2bfloat16(0.f)
                                : __float2bfloat16(x[idx - 2304]);
    } else if (idx < P_W1F) {
        const int i  = idx - P_XBP;
        const int nti = i / 12288;
        const int r  = i % 12288;
        const int kt = r >> 9;
        const int r2 = r & 511;
        const int l  = r2 >> 3, j0 = r2 & 7;
        const int row = nti * 16 + (l & 15);
        const int col = kt * 32 + (l >> 4) * 8 + j0;
        w1f[i] = __float2bfloat16(w1[row * 768 + col]);
    } else if (idx < P_W1BT) {
        const int i  = idx - P_W1F;
        const int nti = i >> 14;
        const int r  = i & 16383;
        const int kt = r >> 9;
        const int r2 = r & 511;
        const int l  = r2 >> 3, j0 = r2 & 7;
        const int j  = nti * 16 + (l & 15);
        const int k  = kt * 32 + (l >> 4) * 8 + j0;
        w1bT[i] = __float2bfloat16(w1[(1024 + k) * 768 + j]);
    } else if (idx < P_CWR) {
        const int n   = idx - P_W1BT;
        const int row = n >> 10;
        const int i   = n & 1023;
        const int s   = row >> 10;
        const int o   = row & 1023;
        cwr[n] = __float2bfloat16(conv_w[o * 4096 + i * 4 + s]);
    } else if (idx < P_WRG) {
        const int i  = idx - P_CWR;
        const int nti = i >> 14;
        const int r  = i & 16383;
        const int kt = r >> 9;
        const int r2 = r & 511;
        const int l  = r2 >> 3, j0 = r2 & 7;
        const int row = nti * 16 + (l & 15);
        const int col = kt * 32 + (l >> 4) * 8 + j0;
        w_rgf[i] = __float2bfloat16(w_rg[row * 1024 + col]);
    } else {
        const int i  = idx - P_WRG;
        const int nti = i >> 14;
        const int r  = i & 16383;
        const int kt = r >> 9;
        const int r2 = r & 511;
        const int l  = r2 >> 3, j0 = r2 & 7;
        const int row = nti * 16 + (l & 15);
        const int col = kt * 32 + (l >> 4) * 8 + j0;
        w_outf[i] = __float2bfloat16(w_out[row * 1024 + col]);
    }
}

// Gates recomputed inline from g_pre (T x 2048 bf16) + bc (bf16):
__global__ void scan_pass1(const __hip_bfloat16* __restrict__ gp,
                           const __hip_bfloat16* __restrict__ bc,
                           const float* __restrict__ Lambda,
                           float* __restrict__ ch, float* __restrict__ ca)
{
    const int c = blockIdx.y * 256 + threadIdx.x;
    const int j = blockIdx.x;
    const float cl = -8.f * log1pf(expf(Lambda[c]));
    float h = 0.f, ap = 1.f;
    const int t0 = j * CL;
    for (int tt = 0; tt < CL; ++tt) {
        const int t = t0 + tt;
        const long gi = (long)t * 2048 + c;
        const float ig = 1.f / (1.f + expf(-__bfloat162float(gp[gi])));
        const float rg = 1.f / (1.f + expf(-__bfloat162float(gp[gi + 1024])));
        const float a  = expf(cl * rg);
        const float gx = sqrtf(fmaxf(0.f, 1.f - a * a)) * ig *
                         __bfloat162float(bc[(long)t * 1024 + c]);
        h  = fmaf(a, h, gx);
        ap *= a;
    }
    ch[j * 1024 + c] = h;
    ca[j * 1024 + c] = ap;
}

__global__ void scan_combine(float* __restrict__ ch, const float* __restrict__ ca)
{
    const int c = blockIdx.x * 256 + threadIdx.x;
    float carry = 0.f;
    for (int j = 0; j < NC; ++j) {
        const float hj = ch[j * 1024 + c];
        const float aj = ca[j * 1024 + c];
        ch[j * 1024 + c] = carry;
        carry = fmaf(aj, carry, hj);
    }
}

// Rescan with carry; z = ab * y -> bf16 (zb aliases bc: same-element RMW per thread).
__global__ void scan_pass2(const __hip_bfloat16* __restrict__ gp, const __hip_bfloat16* bc,
                           const float* __restrict__ Lambda,
                           const float* __restrict__ carry_in,
                           const __hip_bfloat16* __restrict__ ab,
                           __hip_bfloat16* zb)
{
    const int c = blockIdx.y * 256 + threadIdx.x;
    const int j = blockIdx.x;
    const float cl = -8.f * log1pf(expf(Lambda[c]));
    float h = carry_in[j * 1024 + c];
    const int t0 = j * CL;
    for (int tt = 0; tt < CL; ++tt) {
        const int t = t0 + tt;
        const long gi = (long)t * 2048 + c;
        const long bi = (long)t * 1024 + c;
        const float ig = 1.f / (1.f + expf(-__bfloat162float(gp[gi])));
        const float rg = 1.f / (1.f + expf(-__bfloat162float(gp[gi + 1024])));
        const float a  = expf(cl * rg);
        const float gx = sqrtf(fmaxf(0.f, 1.f - a * a)) * ig * __bfloat162float(bc[bi]);
        h = fmaf(a, h, gx);
        zb[bi] = __float2bfloat16(__bfloat162float(ab[bi]) * h);
    }
}

extern "C" void kernel_launch(void* const* d_in, const int* in_sizes, int n_in,
                              void* d_out, int out_size, void* d_ws, size_t ws_size,
                              hipStream_t stream)
{
    const float* x      = (const float*)d_in[0];
    const float* w1     = (const float*)d_in[1];
    const float* b1     = (const float*)d_in[2];
    const float* conv_w = (const float*)d_in[3];
    const float* w_rg   = (const float*)d_in[4];
    const float* b_rg   = (const float*)d_in[5];
    const float* w_out  = (const float*)d_in[6];
    const float* b_out  = (const float*)d_in[7];
    const float* Lambda = (const float*)d_in[8];
    float* out = (float*)d_out;
    (void)in_sizes; (void)n_in; (void)out_size; (void)ws_size;

    // ---- workspace layout (~105 MB) ----
    char* p = (char*)d_ws;
    auto alloc = [&](size_t bytes) { char* r = p; p += (bytes + 255) & ~255ULL; return r; };
    __hip_bfloat16* gpre  = (__hip_bfloat16*)alloc(8192ULL * 2048 * 2); // 32 MB
    __hip_bfloat16* ab    = (__hip_bfloat16*)alloc(8192ULL * 1024 * 2); // 16 MB
    __hip_bfloat16* xbp   = (__hip_bfloat16*)alloc(8200ULL * 768 * 2);  // 12.6 MB
    __hip_bfloat16* bcb   = (__hip_bfloat16*)alloc(8192ULL * 1024 * 2); // 16 MB (later zb)
    __hip_bfloat16* WBf   = (__hip_bfloat16*)alloc(1024ULL * 4 * 768 * 2); // 6.3 MB
    __hip_bfloat16* cwr   = (__hip_bfloat16*)alloc(4096ULL * 1024 * 2); // 8.4 MB
    __hip_bfloat16* w1f   = (__hip_bfloat16*)alloc(1024ULL * 768 * 2);  // 1.5 MB
    __hip_bfloat16* w1bT  = (__hip_bfloat16*)alloc(768ULL * 1024 * 2);  // 1.5 MB
    __hip_bfloat16* w_rgf = (__hip_bfloat16*)alloc(2048ULL * 1024 * 2); // 4 MB
    __hip_bfloat16* w_outf= (__hip_bfloat16*)alloc(768ULL * 1024 * 2);  // 1.5 MB
    float*          chv   = (float*)alloc(NC * 1024ULL * 4);            // 1 MB
    float*          cav   = (float*)alloc(NC * 1024ULL * 4);            // 1 MB
    __hip_bfloat16* zb    = bcb;   // overlay

    prep1_kernel<<<P_TOT / 256, 256, 0, stream>>>(x, w1, w_rg, w_out, conv_w,
                                                  xbp, w1f, w1bT, cwr, w_rgf, w_outf);

    // V = conv_w (*) w1b, written DIRECTLY into conv frag-major WBf (EPI=3)
    {
        dim3 grid(4096 / 128, 768 / 64);
        gemm_mfma<3><<<grid, 256, 0, stream>>>(cwr, w1bT, nullptr, WBf, 1024, 1024, 768, nullptr);
    }

    // ab = bf16(gelu(x @ w1a.T + b1a))  (gelu half only, N=1024)
    {
        dim3 grid(T_LEN / 128, 1024 / 64);
        gemm_mfma<2><<<grid, 256, 0, stream>>>(xbp + 2304, w1f, b1, ab, DM, DM, 1024, nullptr);
    }

    // bc = sum_s V_s @ x[t+s-3]  (conv directly from padded x)
    {
        dim3 grid(T_LEN / 128, 1024 / 64);
        convx_mfma<<<grid, 256, 0, stream>>>(xbp, WBf, bcb);
    }

    // g_pre = bc @ w_rg.T + b_rg -> bf16
    {
        dim3 grid(T_LEN / 128, 2048 / 64);
        gemm_mfma<1><<<grid, 256, 0, stream>>>(bcb, w_rgf, b_rg, gpre, DR, DR, 2048, nullptr);
    }

    // chunked scan with fused gates; z = ab*y -> bf16 (overlays bcb)
    {
        dim3 gs(NC, DR / 256);
        scan_pass1<<<gs, 256, 0, stream>>>(gpre, bcb, Lambda, chv, cav);
        scan_combine<<<DR / 256, 256, 0, stream>>>(chv, cav);
        scan_pass2<<<gs, 256, 0, stream>>>(gpre, bcb, Lambda, chv, ab, zb);
    }

    // out = z @ w_out.T + b_out -> fp32
    {
        dim3 grid(T_LEN / 128, DM / 64);
        gemm_mfma<0><<<grid, 256, 0, stream>>>(zb, w_outf, b_out, out, DR, DR, DM, nullptr);
    }
}

// Round 17
// 240.910 us; speedup vs baseline: 1.0417x; 1.0417x over previous
//
#include <hip/hip_runtime.h>
#include <hip/hip_bf16.h>
#include <stdint.h>

// ---------------------------------------------------------------------------
// RG-LRU block: T=8192, D_MODEL=768, D_RNN=1024, KW=4.
// Round 21 = R15 (best, 247.2us) + two fixes:
//  - prep1 vectorized: 8 elements/thread, bf16x8 stores (was scalar 2B
//    stores, partial-sector; Common-mistake #2).  7298 blocks (was 58377).
//  - convx reverted to R15's BN=128 2-blk form (R16's 4-blk BN=64 was null).
// Everything else byte-identical to R15.
// ---------------------------------------------------------------------------

#define T_LEN 8192
#define DM 768
#define DR 1024
#define NC 256   // scan chunks
#define CL 32    // chunk length

typedef __bf16 bf16x8 __attribute__((ext_vector_type(8)));
typedef float  f32x4  __attribute__((ext_vector_type(4)));

#define AS1 __attribute__((address_space(1)))
#define AS3 __attribute__((address_space(3)))

__device__ __forceinline__ void cp16_g2l(const void* g, void* l) {
    __builtin_amdgcn_global_load_lds((const AS1 void*)g, (AS3 void*)l, 16, 0, 0);
}

__device__ __forceinline__ float gelu_tanh(float x) {
    const float inner = 0.7978845608028654f * (x + 0.044715f * x * x * x);
    return 0.5f * x * (1.f + tanhf(inner));
}

__device__ __forceinline__ __bf16 f2b(float v) {
    __hip_bfloat16 h = __float2bfloat16(v);
    return *reinterpret_cast<__bf16*>(&h);
}

// ---------------------------------------------------------------------------
// Dense GEMM (R15-verified), BN=64, BK=64/iter, 4 blocks/CU.
// A: LDS dbuf [2][128*64]; 8 chunks/row; slot s of row r holds chunk s^(r&7).
// B: fragment-major WF [ntile][kt][lane][16B]; 2 ksteps x NI=2 frags jit.
// EPI: 0 = fp32 +bias; 1 = bf16 +bias; 2 = bf16 gelu (stride-1024);
//      3 = bf16 -> conv frag-major WBf (Vgemm).
// ---------------------------------------------------------------------------
template<int EPI>
__global__ __launch_bounds__(256, 4)
void gemm_mfma(const __hip_bfloat16* __restrict__ A,
               const __hip_bfloat16* __restrict__ WF,
               const float* __restrict__ bias,
               void* __restrict__ Cv,
               int K, int lda, int N,
               __hip_bfloat16* __restrict__ D2)
{
    __shared__ __align__(16) unsigned char smem[32768];
    __bf16* Asb = (__bf16*)smem;           // [2][128*64] = 32KB

    const int tid  = threadIdx.x;
    const int lane = tid & 63;
    const int wave = tid >> 6;
    const size_t m0 = (size_t)blockIdx.x * 128;
    const int    n0 = blockIdx.y * 64;
    const int wm = (wave >> 1) * 64;
    const int wn = (wave & 1) * 32;

    f32x4 acc[4][2];
#pragma unroll
    for (int i = 0; i < 4; ++i)
#pragma unroll
        for (int j = 0; j < 2; ++j)
            acc[i][j] = f32x4{0.f, 0.f, 0.f, 0.f};

    const int frow = lane & 15;
    const int fq   = lane >> 4;
    const int NKT  = K >> 5;                // 32-col k-steps
    const int nt   = K >> 6;                // 64-col iterations

    const __bf16* wbase = (const __bf16*)WF +
        (((size_t)((n0 + wn) >> 4) * NKT) << 9) + (lane << 3);

    auto stageA = [&](int buf, int k0) {   // 128 rows x 8 chunks = 1024 chunks
#pragma unroll
        for (int q = 0; q < 4; ++q) {
            const int lin = q * 256 + tid;
            const int rr  = lin >> 3;
            const int gc  = (lin & 7) ^ (rr & 7);
            cp16_g2l(A + (m0 + rr) * (size_t)lda + k0 + gc * 8,
                     Asb + buf * 8192 + lin * 8);
        }
    };

    stageA(0, 0);
#pragma unroll 1
    for (int t = 0; t < nt; ++t) {
        bf16x8 bfr[2][2];
#pragma unroll
        for (int ks = 0; ks < 2; ++ks)
#pragma unroll
            for (int ni = 0; ni < 2; ++ni)
                bfr[ks][ni] = *(const bf16x8*)(wbase +
                    (((size_t)(ni * NKT + 2 * t + ks)) << 9));
        if (t + 1 < nt) {
            stageA((t + 1) & 1, (t + 1) * 64);
            // FIFO: [A(t):4][B(t):4][A(t+1):4]; vmcnt(4) retires A(t)+B(t)
            asm volatile("s_waitcnt vmcnt(4)" ::: "memory");
        } else {
            asm volatile("s_waitcnt vmcnt(0)" ::: "memory");
        }
        __builtin_amdgcn_sched_barrier(0);
        __builtin_amdgcn_s_barrier();          // A[t&1] staged for all waves
        __builtin_amdgcn_sched_barrier(0);

        const int ab = (t & 1) * 8192;
        bf16x8 af[2][4];
#pragma unroll
        for (int ks = 0; ks < 2; ++ks)
#pragma unroll
            for (int mi = 0; mi < 4; ++mi) {
                const int R = wm + mi * 16 + frow;
                af[ks][mi] = *(const bf16x8*)&Asb[ab + R * 64 +
                                                  (((ks * 4 + fq) ^ (R & 7)) * 8)];
            }
        asm volatile("s_waitcnt lgkmcnt(0)" ::: "memory");
        __builtin_amdgcn_sched_barrier(0);
        __builtin_amdgcn_s_setprio(1);
#pragma unroll
        for (int ks = 0; ks < 2; ++ks)
#pragma unroll
            for (int mi = 0; mi < 4; ++mi)
#pragma unroll
                for (int ni = 0; ni < 2; ++ni)
                    acc[mi][ni] = __builtin_amdgcn_mfma_f32_16x16x32_bf16(
                        af[ks][mi], bfr[ks][ni], acc[mi][ni], 0, 0, 0);
        __builtin_amdgcn_s_setprio(0);
        __builtin_amdgcn_sched_barrier(0);
        __builtin_amdgcn_s_barrier();          // A[t&1] free for overwrite
        __builtin_amdgcn_sched_barrier(0);
    }

    // ---- epilogue: acc -> swizzled LDS -> coalesced 16B/lane global stores.
    __syncthreads();
    const int er = fq * 4;
    const int ec = frow;

    if (EPI == 0) {
        float* Cl = (float*)smem;
#pragma unroll
        for (int ni = 0; ni < 2; ++ni) {
            const int cc = wn + ni * 16 + ec;
            const float bv = bias ? bias[n0 + cc] : 0.f;
#pragma unroll
            for (int mi = 0; mi < 4; ++mi)
#pragma unroll
                for (int r2 = 0; r2 < 4; ++r2) {
                    const int R = wm + mi * 16 + er + r2;
                    Cl[R * 64 + ((((cc >> 2) ^ (R & 7)) << 2) | (cc & 3))] =
                        acc[mi][ni][r2] + bv;
                }
        }
        __syncthreads();
        float* outp = (float*)Cv;
#pragma unroll
        for (int p = 0; p < 8; ++p) {
            const int R   = (tid >> 4) + p * 16;
            const int chn = tid & 15;
            const f32x4 v = *(const f32x4*)&Cl[R * 64 + ((chn ^ (R & 7)) << 2)];
            *(f32x4*)&outp[(m0 + R) * (size_t)N + n0 + chn * 4] = v;
        }
    } else {
        __bf16* Cl = (__bf16*)smem;
#pragma unroll
        for (int ni = 0; ni < 2; ++ni) {
            const int cc = wn + ni * 16 + ec;
            const float bv = bias ? bias[n0 + cc] : 0.f;
#pragma unroll
            for (int mi = 0; mi < 4; ++mi)
#pragma unroll
                for (int r2 = 0; r2 < 4; ++r2) {
                    const int R = wm + mi * 16 + er + r2;
                    float v = acc[mi][ni][r2] + bv;
                    if (EPI == 2) v = gelu_tanh(v);
                    Cl[R * 64 + ((((cc >> 3) ^ (R & 7)) << 3) | (cc & 7))] = f2b(v);
                }
        }
        __syncthreads();
#pragma unroll
        for (int p = 0; p < 4; ++p) {
            const int R   = (tid >> 3) + p * 32;
            const int chn = tid & 7;
            const bf16x8 v = *(const bf16x8*)&Cl[R * 64 + ((chn ^ (R & 7)) << 3)];
            if (EPI == 1) {
                *(bf16x8*)((__bf16*)Cv + (m0 + R) * (size_t)N + n0 + chn * 8) = v;
            } else if (EPI == 2) {
                *(bf16x8*)((__bf16*)Cv + (m0 + R) * 1024 + n0 + chn * 8) = v;
            } else {
                // EPI==3: conv frag-major WBf.  m = s*1024+o, j = col.
                const int m  = (int)(m0 + R);
                const int s  = m >> 10;
                const int o  = m & 1023;
                const int j  = n0 + chn * 8;
                const size_t dst = (size_t)(o >> 4) * 49152 + (size_t)(j >> 5) * 2048 +
                                   s * 512 + ((((j >> 3) & 3) * 16 + (o & 15)) << 3);
                *(bf16x8*)((__bf16*)Cv + dst) = v;
            }
        }
    }
    (void)D2;
}

// ---------------------------------------------------------------------------
// convx (R15-verified): bc[t,o] = sum_s sum_j V[s][o][j]*xbp[t+s][j].
// R8 conv structure, K=768/shift (24 k-iters); B-frags global->register from
// WBf [nt][kcI<24][s][lane][8]; A-halo (132x32) LDS dbuf; 64 MFMA/wave per
// barrier-pair; vmcnt(16); 2 blocks/CU.
// ---------------------------------------------------------------------------
__global__ __launch_bounds__(256, 2)
void convx_mfma(const __hip_bfloat16* __restrict__ xbp,
                const __hip_bfloat16* __restrict__ WBf,
                __hip_bfloat16* __restrict__ C)
{
    __shared__ __align__(16) unsigned char smem[32768];
    __bf16* Ah = (__bf16*)smem;             // [2][132*32] halo dbuf (16.9KB)

    const int tid  = threadIdx.x;
    const int lane = tid & 63;
    const int wave = tid >> 6;
    const size_t m0 = (size_t)blockIdx.x * 128;
    const int    n0 = blockIdx.y * 128;
    const int wm = (wave >> 1) * 64;
    const int wn = (wave & 1) * 64;

    f32x4 acc[4][4];
#pragma unroll
    for (int i = 0; i < 4; ++i)
#pragma unroll
        for (int j = 0; j < 4; ++j)
            acc[i][j] = f32x4{0.f, 0.f, 0.f, 0.f};

    const int frow = lane & 15;
    const int fq   = lane >> 4;

    const __bf16* wbase = (const __bf16*)WBf +
        (size_t)((n0 + wn) >> 4) * 49152 + (lane << 3);

    auto loadB = [&](bf16x8 (&b)[4][4], int t1) {
#pragma unroll
        for (int s = 0; s < 4; ++s)
#pragma unroll
            for (int ni = 0; ni < 4; ++ni)
                b[s][ni] = *(const bf16x8*)(wbase + (size_t)ni * 49152 +
                                            t1 * 2048 + s * 512);
    };
    auto stageA = [&](int abuf, int kc) {   // 132 rows x 4 chunks = 528 chunks
#pragma unroll
        for (int q = 0; q < 2; ++q) {
            const int lin = q * 256 + tid;
            const int rr  = lin >> 2;
            const int gc  = (lin & 3) ^ ((rr >> 1) & 3);
            cp16_g2l(xbp + (m0 + rr) * 768 + kc + gc * 8, Ah + abuf * 4224 + lin * 8);
        }
        if (tid < 16) {
            const int lin = 512 + tid;
            const int rr  = lin >> 2;
            const int gc  = (lin & 3) ^ ((rr >> 1) & 3);
            cp16_g2l(xbp + (m0 + rr) * 768 + kc + gc * 8, Ah + abuf * 4224 + lin * 8);
        }
    };

    bf16x8 bA[4][4], bB[4][4];
    stageA(0, 0);
    loadB(bA, 0);

    auto iter = [&](bf16x8 (&bCur)[4][4], bf16x8 (&bNxt)[4][4], int t) {
        if (t + 1 < 24) {
            loadB(bNxt, t + 1);
            asm volatile("s_waitcnt vmcnt(16)" ::: "memory");
        } else {
            asm volatile("s_waitcnt vmcnt(0)" ::: "memory");
        }
        __builtin_amdgcn_sched_barrier(0);
        __builtin_amdgcn_s_barrier();          // halo[t&1] staged for all waves
        __builtin_amdgcn_sched_barrier(0);

        const int ab = (t & 1) * 4224;
        __builtin_amdgcn_s_setprio(1);
#pragma unroll
        for (int s = 0; s < 4; ++s) {
            bf16x8 af[4];
#pragma unroll
            for (int mi = 0; mi < 4; ++mi) {
                const int R = wm + mi * 16 + frow + s;       // shifted halo row
                af[mi] = *(const bf16x8*)&Ah[ab + R * 32 + ((fq ^ ((R >> 1) & 3)) * 8)];
            }
#pragma unroll
            for (int mi = 0; mi < 4; ++mi)
#pragma unroll
                for (int ni = 0; ni < 4; ++ni)
                    acc[mi][ni] = __builtin_amdgcn_mfma_f32_16x16x32_bf16(
                        af[mi], bCur[s][ni], acc[mi][ni], 0, 0, 0);
        }
        __builtin_amdgcn_s_setprio(0);
        __builtin_amdgcn_sched_barrier(0);
        __builtin_amdgcn_s_barrier();          // halo[t&1] free for overwrite
        __builtin_amdgcn_sched_barrier(0);
        if (t + 1 < 24) stageA((t + 1) & 1, (t + 1) * 32);
    };

#pragma unroll 1
    for (int tp = 0; tp < 12; ++tp) {
        iter(bA, bB, 2 * tp);
        iter(bB, bA, 2 * tp + 1);
    }

    // ---- epilogue: bf16 tile 128x128 via swizzled LDS, coalesced stores.
    __syncthreads();
    const int er = fq * 4;
    const int ec = frow;
    __bf16* Cl = (__bf16*)smem;
#pragma unroll
    for (int ni = 0; ni < 4; ++ni) {
        const int cc = wn + ni * 16 + ec;
#pragma unroll
        for (int mi = 0; mi < 4; ++mi)
#pragma unroll
            for (int r2 = 0; r2 < 4; ++r2) {
                const int R = wm + mi * 16 + er + r2;
                Cl[R * 128 + ((((cc >> 3) ^ (R & 7)) << 3) | (cc & 7))] =
                    f2b(acc[mi][ni][r2]);
            }
    }
    __syncthreads();
#pragma unroll
    for (int p = 0; p < 8; ++p) {
        const int R   = (tid >> 4) + p * 16;
        const int chn = tid & 15;
        const bf16x8 v = *(const bf16x8*)&Cl[R * 128 + ((chn ^ (R & 7)) << 3)];
        *(bf16x8*)((__bf16*)C + (m0 + R) * 1024 + n0 + chn * 8) = v;
    }
}

// ---------------------------------------------------------------------------
// prep1, vectorized 8 elems/thread (all segment bases and j0-runs are
// 8-aligned; dest is always one contiguous bf16x8 store):
// xbp (3 zero rows) + w1f (gelu half) + w1bT (Vgemm B) + cwr (Vgemm A) +
// w_rgf + w_outf.
// ---------------------------------------------------------------------------
#define P_XBP  6293760              // 8195*768
#define P_W1F  (P_XBP + 786432)     // 64nt * 24kt * 512
#define P_W1BT (P_W1F + 786432)     // 48nt * 32kt * 512
#define P_CWR  (P_W1BT + 4194304)   // 4096*1024
#define P_WRG  (P_CWR + 2097152)    // 128nt * 32kt * 512
#define P_WO   (P_WRG + 786432)     // 48nt * 32kt * 512
#define P_TOT  P_WO                 // 14,944,512
__global__ void prep1_kernel(const float* __restrict__ x, const float* __restrict__ w1,
                             const float* __restrict__ w_rg, const float* __restrict__ w_out,
                             const float* __restrict__ conv_w,
                             __hip_bfloat16* __restrict__ xbp, __hip_bfloat16* __restrict__ w1f,
                             __hip_bfloat16* __restrict__ w1bT, __hip_bfloat16* __restrict__ cwr,
                             __hip_bfloat16* __restrict__ w_rgf, __hip_bfloat16* __restrict__ w_outf)
{
    const long e = ((long)blockIdx.x * 256 + threadIdx.x) * 8;
    if (e >= P_TOT) return;
    bf16x8 v;
    if (e < P_XBP) {
        if (e < 2304) {
#pragma unroll
            for (int j = 0; j < 8; ++j) v[j] = f2b(0.f);
        } else {
            const float* s = x + (e - 2304);
#pragma unroll
            for (int j = 0; j < 8; ++j) v[j] = f2b(s[j]);
        }
        *(bf16x8*)&xbp[e] = v;
    } else if (e < P_W1F) {
        const int i  = (int)(e - P_XBP);
        const int nti = i / 12288;
        const int r  = i % 12288;
        const int kt = r >> 9;
        const int l  = (r & 511) >> 3;
        const int row = nti * 16 + (l & 15);
        const int col = kt * 32 + (l >> 4) * 8;
        const float* s = w1 + row * 768 + col;
#pragma unroll
        for (int j = 0; j < 8; ++j) v[j] = f2b(s[j]);
        *(bf16x8*)&w1f[i] = v;
    } else if (e < P_W1BT) {
        const int i  = (int)(e - P_W1F);
        const int nti = i >> 14;
        const int r  = i & 16383;
        const int kt = r >> 9;
        const int l  = (r & 511) >> 3;
        const int jj = nti * 16 + (l & 15);
        const int k0 = kt * 32 + (l >> 4) * 8;
#pragma unroll
        for (int j = 0; j < 8; ++j) v[j] = f2b(w1[(1024 + k0 + j) * 768 + jj]);
        *(bf16x8*)&w1bT[i] = v;
    } else if (e < P_CWR) {
        const int n   = (int)(e - P_W1BT);
        const int row = n >> 10;
        const int i0  = n & 1023;
        const int s   = row >> 10;
        const int o   = row & 1023;
#pragma unroll
        for (int j = 0; j < 8; ++j) v[j] = f2b(conv_w[o * 4096 + (i0 + j) * 4 + s]);
        *(bf16x8*)&cwr[n] = v;
    } else if (e < P_WRG) {
        const int i  = (int)(e - P_CWR);
        const int nti = i >> 14;
        const int r  = i & 16383;
        const int kt = r >> 9;
        const int l  = (r & 511) >> 3;
        const int row = nti * 16 + (l & 15);
        const int col = kt * 32 + (l >> 4) * 8;
        const float* s = w_rg + row * 1024 + col;
#pragma unroll
        for (int j = 0; j < 8; ++j) v[j] = f2b(s[j]);
        *(bf16x8*)&w_rgf[i] = v;
    } else {
        const int i  = (int)(e - P_WRG);
        const int nti = i >> 14;
        const int r  = i & 16383;
        const int kt = r >> 9;
        const int l  = (r & 511) >> 3;
        const int row = nti * 16 + (l & 15);
        const int col = kt * 32 + (l >> 4) * 8;
        const float* s = w_out + row * 1024 + col;
#pragma unroll
        for (int j = 0; j < 8; ++j) v[j] = f2b(s[j]);
        *(bf16x8*)&w_outf[i] = v;
    }
}

// Gates recomputed inline from g_pre (T x 2048 bf16) + bc (bf16):
__global__ void scan_pass1(const __hip_bfloat16* __restrict__ gp,
                           const __hip_bfloat16* __restrict__ bc,
                           const float* __restrict__ Lambda,
                           float* __restrict__ ch, float* __restrict__ ca)
{
    const int c = blockIdx.y * 256 + threadIdx.x;
    const int j = blockIdx.x;
    const float cl = -8.f * log1pf(expf(Lambda[c]));
    float h = 0.f, ap = 1.f;
    const int t0 = j * CL;
    for (int tt = 0; tt < CL; ++tt) {
        const int t = t0 + tt;
        const long gi = (long)t * 2048 + c;
        const float ig = 1.f / (1.f + expf(-__bfloat162float(gp[gi])));
        const float rg = 1.f / (1.f + expf(-__bfloat162float(gp[gi + 1024])));
        const float a  = expf(cl * rg);
        const float gx = sqrtf(fmaxf(0.f, 1.f - a * a)) * ig *
                         __bfloat162float(bc[(long)t * 1024 + c]);
        h  = fmaf(a, h, gx);
        ap *= a;
    }
    ch[j * 1024 + c] = h;
    ca[j * 1024 + c] = ap;
}

__global__ void scan_combine(float* __restrict__ ch, const float* __restrict__ ca)
{
    const int c = blockIdx.x * 256 + threadIdx.x;
    float carry = 0.f;
    for (int j = 0; j < NC; ++j) {
        const float hj = ch[j * 1024 + c];
        const float aj = ca[j * 1024 + c];
        ch[j * 1024 + c] = carry;
        carry = fmaf(aj, carry, hj);
    }
}

// Rescan with carry; z = ab * y -> bf16 (zb aliases bc: same-element RMW per thread).
__global__ void scan_pass2(const __hip_bfloat16* __restrict__ gp, const __hip_bfloat16* bc,
                           const float* __restrict__ Lambda,
                           const float* __restrict__ carry_in,
                           const __hip_bfloat16* __restrict__ ab,
                           __hip_bfloat16* zb)
{
    const int c = blockIdx.y * 256 + threadIdx.x;
    const int j = blockIdx.x;
    const float cl = -8.f * log1pf(expf(Lambda[c]));
    float h = carry_in[j * 1024 + c];
    const int t0 = j * CL;
    for (int tt = 0; tt < CL; ++tt) {
        const int t = t0 + tt;
        const long gi = (long)t * 2048 + c;
        const long bi = (long)t * 1024 + c;
        const float ig = 1.f / (1.f + expf(-__bfloat162float(gp[gi])));
        const float rg = 1.f / (1.f + expf(-__bfloat162float(gp[gi + 1024])));
        const float a  = expf(cl * rg);
        const float gx = sqrtf(fmaxf(0.f, 1.f - a * a)) * ig * __bfloat162float(bc[bi]);
        h = fmaf(a, h, gx);
        zb[bi] = __float2bfloat16(__bfloat162float(ab[bi]) * h);
    }
}

extern "C" void kernel_launch(void* const* d_in, const int* in_sizes, int n_in,
                              void* d_out, int out_size, void* d_ws, size_t ws_size,
                              hipStream_t stream)
{
    const float* x      = (const float*)d_in[0];
    const float* w1     = (const float*)d_in[1];
    const float* b1     = (const float*)d_in[2];
    const float* conv_w = (const float*)d_in[3];
    const float* w_rg   = (const float*)d_in[4];
    const float* b_rg   = (const float*)d_in[5];
    const float* w_out  = (const float*)d_in[6];
    const float* b_out  = (const float*)d_in[7];
    const float* Lambda = (const float*)d_in[8];
    float* out = (float*)d_out;
    (void)in_sizes; (void)n_in; (void)out_size; (void)ws_size;

    // ---- workspace layout (~105 MB) ----
    char* p = (char*)d_ws;
    auto alloc = [&](size_t bytes) { char* r = p; p += (bytes + 255) & ~255ULL; return r; };
    __hip_bfloat16* gpre  = (__hip_bfloat16*)alloc(8192ULL * 2048 * 2); // 32 MB
    __hip_bfloat16* ab    = (__hip_bfloat16*)alloc(8192ULL * 1024 * 2); // 16 MB
    __hip_bfloat16* xbp   = (__hip_bfloat16*)alloc(8200ULL * 768 * 2);  // 12.6 MB
    __hip_bfloat16* bcb   = (__hip_bfloat16*)alloc(8192ULL * 1024 * 2); // 16 MB (later zb)
    __hip_bfloat16* WBf   = (__hip_bfloat16*)alloc(1024ULL * 4 * 768 * 2); // 6.3 MB
    __hip_bfloat16* cwr   = (__hip_bfloat16*)alloc(4096ULL * 1024 * 2); // 8.4 MB
    __hip_bfloat16* w1f   = (__hip_bfloat16*)alloc(1024ULL * 768 * 2);  // 1.5 MB
    __hip_bfloat16* w1bT  = (__hip_bfloat16*)alloc(768ULL * 1024 * 2);  // 1.5 MB
    __hip_bfloat16* w_rgf = (__hip_bfloat16*)alloc(2048ULL * 1024 * 2); // 4 MB
    __hip_bfloat16* w_outf= (__hip_bfloat16*)alloc(768ULL * 1024 * 2);  // 1.5 MB
    float*          chv   = (float*)alloc(NC * 1024ULL * 4);            // 1 MB
    float*          cav   = (float*)alloc(NC * 1024ULL * 4);            // 1 MB
    __hip_bfloat16* zb    = bcb;   // overlay

    prep1_kernel<<<(P_TOT / 8 + 255) / 256, 256, 0, stream>>>(
        x, w1, w_rg, w_out, conv_w, xbp, w1f, w1bT, cwr, w_rgf, w_outf);

    // V = conv_w (*) w1b, written DIRECTLY into conv frag-major WBf (EPI=3)
    {
        dim3 grid(4096 / 128, 768 / 64);
        gemm_mfma<3><<<grid, 256, 0, stream>>>(cwr, w1bT, nullptr, WBf, 1024, 1024, 768, nullptr);
    }

    // ab = bf16(gelu(x @ w1a.T + b1a))  (gelu half only, N=1024)
    {
        dim3 grid(T_LEN / 128, 1024 / 64);
        gemm_mfma<2><<<grid, 256, 0, stream>>>(xbp + 2304, w1f, b1, ab, DM, DM, 1024, nullptr);
    }

    // bc = sum_s V_s @ x[t+s-3]  (conv directly from padded x)
    {
        dim3 grid(T_LEN / 128, 1024 / 128);
        convx_mfma<<<grid, 256, 0, stream>>>(xbp, WBf, bcb);
    }

    // g_pre = bc @ w_rg.T + b_rg -> bf16
    {
        dim3 grid(T_LEN / 128, 2048 / 64);
        gemm_mfma<1><<<grid, 256, 0, stream>>>(bcb, w_rgf, b_rg, gpre, DR, DR, 2048, nullptr);
    }

    // chunked scan with fused gates; z = ab*y -> bf16 (overlays bcb)
    {
        dim3 gs(NC, DR / 256);
        scan_pass1<<<gs, 256, 0, stream>>>(gpre, bcb, Lambda, chv, cav);
        scan_combine<<<DR / 256, 256, 0, stream>>>(chv, cav);
        scan_pass2<<<gs, 256, 0, stream>>>(gpre, bcb, Lambda, chv, ab, zb);
    }

    // out = z @ w_out.T + b_out -> fp32
    {
        dim3 grid(T_LEN / 128, DM / 64);
        gemm_mfma<0><<<grid, 256, 0, stream>>>(zb, w_outf, b_out, out, DR, DR, DM, nullptr);
    }
}